// Round 1
// baseline (1084.621 us; speedup 1.0000x reference)
//
#include <hip/hip_runtime.h>
#include <cstdint>
#include <cstddef>

typedef unsigned short u16t;
typedef __attribute__((ext_vector_type(8))) short bf16x8;  // 8 bf16 in 4 VGPRs
typedef __attribute__((ext_vector_type(4))) float f32x4;

#define NNODES 50000
#define NEDGES 800000
#define NP 50176   // 196 * 256, padded node rows

#define MFMA(a, b, c) __builtin_amdgcn_mfma_f32_16x16x32_bf16((a), (b), (c), 0, 0, 0)

__device__ inline float b2f(short s) {
    union { float f; unsigned int u; } c;
    c.u = ((unsigned int)(unsigned short)s) << 16;
    return c.f;
}
__device__ inline short f2b(float f) {
    union { float f; unsigned int u; } c; c.f = f;
    unsigned int u = c.u;
    unsigned int r = (u + 0x7FFFu + ((u >> 16) & 1u)) >> 16;  // RNE
    return (short)(unsigned short)r;
}
__device__ inline f32x4 zero4() { f32x4 z = {0.f, 0.f, 0.f, 0.f}; return z; }

// load 8 consecutive f32 and round to bf16x8 (A/B fragment builder)
__device__ inline bf16x8 ld8f(const float* p) {
    float4 a = *(const float4*)p;
    float4 b = *(const float4*)(p + 4);
    bf16x8 r;
    r[0] = f2b(a.x); r[1] = f2b(a.y); r[2] = f2b(a.z); r[3] = f2b(a.w);
    r[4] = f2b(b.x); r[5] = f2b(b.y); r[6] = f2b(b.z); r[7] = f2b(b.w);
    return r;
}
// same, with scale (for folding the softmax denominator into the A load)
__device__ inline bf16x8 ld8fs(const float* p, float s) {
    float4 a = *(const float4*)p;
    float4 b = *(const float4*)(p + 4);
    bf16x8 r;
    r[0] = f2b(a.x * s); r[1] = f2b(a.y * s); r[2] = f2b(a.z * s); r[3] = f2b(a.w * s);
    r[4] = f2b(b.x * s); r[5] = f2b(b.y * s); r[6] = f2b(b.z * s); r[7] = f2b(b.w * s);
    return r;
}

__device__ inline float gelu_f(float x) {
    float u = 0.7978845608028654f * (x + 0.044715f * x * x * x);
    float e = __expf(2.f * u);
    return 0.5f * x * (2.f - 2.f / (e + 1.f));
}

// multi-value tree reduce: a[v] per lane, v=0..15; returns (for lane l) the
// sum over its 16-lane group of a[l&15]. 15 shuffles instead of 64.
__device__ inline float tree16(float* a, int l) {
#pragma unroll
    for (int b = 0; b < 4; ++b) {
        const int m = 1 << b;
        const bool up = (l & m) != 0;
#pragma unroll
        for (int j = 0; j < (8 >> b); ++j) {
            float keep = up ? a[2 * j + 1] : a[2 * j];
            float send = up ? a[2 * j] : a[2 * j + 1];
            a[j] = keep + __shfl_xor(send, m);
        }
    }
    return a[0];
}

// ---------------- K0: init accumulators ----------------
__global__ void k_init(float* __restrict__ msg, float* __restrict__ pooled,
                       float* __restrict__ d_n, float* __restrict__ d_e) {
    int i = blockIdx.x * 256 + threadIdx.x;
    if (i < NP * 64) { msg[i] = 0.f; pooled[i] = 0.f; }
    if (i < NP * 4)  { d_n[i] = 0.f; d_e[i] = 0.f; }
}

// ---------------- K1: node projections (bf16 out): qn,kn,vn,nWn ----------------
__global__ __launch_bounds__(256) void k_node_proj(
        const float* __restrict__ nodes,
        const float* __restrict__ Wq, const float* __restrict__ Wk,
        const float* __restrict__ Wv, const float* __restrict__ Wn,
        u16t* __restrict__ qn, u16t* __restrict__ kn,
        u16t* __restrict__ vn, u16t* __restrict__ nWn) {
    __shared__ __align__(16) u16t wt[256 * 72];   // transposed: wt[n][k], stride 72
    {
        const float* Ws[4] = {Wq, Wk, Wv, Wn};
        for (int g = 0; g < 4; ++g) {
            const float* W = Ws[g];
            u16t* dst = wt + g * 64 * 72;
            for (int idx = threadIdx.x; idx < 4096; idx += 256) {
                int n = idx & 63, k = idx >> 6;
                dst[n * 72 + k] = (u16t)f2b(W[idx]);
            }
        }
    }
    __syncthreads();
    int l = threadIdx.x & 63, w = threadIdx.x >> 6;
    int q = l >> 4, c = l & 15;
    int r0 = blockIdx.x * 256 + w * 64;

    bf16x8 A[4][2];
#pragma unroll
    for (int st = 0; st < 4; ++st) {
        int row = r0 + st * 16 + c;
        if (row >= NNODES) row = NNODES - 1;
#pragma unroll
        for (int ks = 0; ks < 2; ++ks)
            A[st][ks] = ld8f(nodes + (size_t)row * 64 + ks * 32 + q * 8);
    }
    u16t* outs[4] = {qn, kn, vn, nWn};
    for (int cg = 0; cg < 4; ++cg) {
        bf16x8 B[2][4];
#pragma unroll
        for (int ks = 0; ks < 2; ++ks)
#pragma unroll
            for (int t = 0; t < 4; ++t)
                B[ks][t] = *(const bf16x8*)(wt + (cg * 64 + t * 16 + c) * 72 + ks * 32 + q * 8);
        float scale = (cg == 0) ? 0.25f : 1.0f;   // fold 1/sqrt(16) into q
        u16t* out = outs[cg];
#pragma unroll
        for (int st = 0; st < 4; ++st) {
            f32x4 acc[4];
#pragma unroll
            for (int t = 0; t < 4; ++t) acc[t] = zero4();
#pragma unroll
            for (int ks = 0; ks < 2; ++ks)
#pragma unroll
                for (int t = 0; t < 4; ++t)
                    acc[t] = MFMA(A[st][ks], B[ks][t], acc[t]);
#pragma unroll
            for (int r = 0; r < 4; ++r) {
                int row = r0 + st * 16 + q * 4 + r;
                if (row < NNODES) {
#pragma unroll
                    for (int t = 0; t < 4; ++t)
                        out[(size_t)row * 64 + t * 16 + c] = (u16t)f2b(acc[t][r] * scale);
                }
            }
        }
    }
}

// ---------------- K2 (fused): scores -> exp -> den atomics
//                  + unnormalized pooled scatter (MFMA layout, ve from MFMA)
//                  + unnormalized msg scatter (feature layout, coalesced vn rows)
__global__ __launch_bounds__(256) void k_edge_fused(
        const float* __restrict__ edges, const int* __restrict__ eidx,
        const float* __restrict__ WeN, const float* __restrict__ WqE,
        const float* __restrict__ WkE, const float* __restrict__ WvE,
        const u16t* __restrict__ qn, const u16t* __restrict__ kn,
        const u16t* __restrict__ nWn, const u16t* __restrict__ vn,
        float* __restrict__ d_n, float* __restrict__ d_e,
        float* __restrict__ msg, float* __restrict__ pooled) {
    __shared__ __align__(16) u16t wt[256 * 72];   // We_n^T | 0.25*Wq_e^T | Wk_e^T | Wv_e^T
    for (int idx = threadIdx.x; idx < 4096; idx += 256) {
        int n = idx & 63, k = idx >> 6;
        wt[n * 72 + k]         = (u16t)f2b(WeN[idx]);
        wt[(64 + n) * 72 + k]  = (u16t)f2b(0.25f * WqE[idx]);  // fold 1/sqrt(16)
        wt[(128 + n) * 72 + k] = (u16t)f2b(WkE[idx]);
        wt[(192 + n) * 72 + k] = (u16t)f2b(WvE[idx]);
    }
    __syncthreads();
    int l = threadIdx.x & 63, w = threadIdx.x >> 6;
    int q = l >> 4, c = l & 15;
    int e0 = blockIdx.x * 256 + w * 64;

    for (int st = 0; st < 4; ++st) {
        int ebase = e0 + st * 16;
        int eA = ebase + c;
        bf16x8 A0 = ld8f(edges + (size_t)eA * 64 + q * 8);
        bf16x8 A1 = ld8f(edges + (size_t)eA * 64 + 32 + q * 8);

        // indices for my 4 accumulator rows (edges ebase + q*4 + r)
        int sr_[4], tg_[4];
#pragma unroll
        for (int r = 0; r < 4; ++r) {
            int e = ebase + q * 4 + r;
            sr_[r] = eidx[e];
            tg_[r] = eidx[NEDGES + e];
        }
        // my owned (edge, head) for score/atomic phase
        int eL = ebase + (l >> 2), hL = l & 3;
        int srL = eidx[eL], tgL = eidx[NEDGES + eL];

        // ---- edge attention scores (aQe/aKe die before pn goes live) ----
        f32x4 aQe[4], aKe[4];
#pragma unroll
        for (int t = 0; t < 4; ++t) { aQe[t] = zero4(); aKe[t] = zero4(); }
#pragma unroll
        for (int t = 0; t < 4; ++t) {
            const u16t* b1 = wt + (64 + t * 16 + c) * 72;
            const u16t* b2 = wt + (128 + t * 16 + c) * 72;
            aQe[t] = MFMA(A0, *(const bf16x8*)(b1 + q * 8), aQe[t]);
            aQe[t] = MFMA(A1, *(const bf16x8*)(b1 + 32 + q * 8), aQe[t]);
            aKe[t] = MFMA(A0, *(const bf16x8*)(b2 + q * 8), aKe[t]);
            aKe[t] = MFMA(A1, *(const bf16x8*)(b2 + 32 + q * 8), aKe[t]);
        }
        float pe[16];
#pragma unroll
        for (int r = 0; r < 4; ++r)
#pragma unroll
            for (int t = 0; t < 4; ++t) {
                int col = t * 16 + c;
                float ng = b2f((short)nWn[(size_t)sr_[r] * 64 + col]);
                pe[r * 4 + t] = aQe[t][r] * (aKe[t][r] + ng);
            }
        float exe = __expf(tree16(pe, l));
        unsafeAtomicAdd(&d_e[srL * 4 + hL], exe);

        // ---- ve = edges@Wv_e; pooled[src] += exe * ve (MFMA layout) ----
        f32x4 aVe[4];
#pragma unroll
        for (int t = 0; t < 4; ++t) aVe[t] = zero4();
#pragma unroll
        for (int t = 0; t < 4; ++t) {
            const u16t* b3 = wt + (192 + t * 16 + c) * 72;
            aVe[t] = MFMA(A0, *(const bf16x8*)(b3 + q * 8), aVe[t]);
            aVe[t] = MFMA(A1, *(const bf16x8*)(b3 + 32 + q * 8), aVe[t]);
        }
#pragma unroll
        for (int r = 0; r < 4; ++r)
#pragma unroll
            for (int t = 0; t < 4; ++t) {
                // owner of (edge q*4+r, head t) is lane (l&48) + r*4 + t
                float a = __shfl(exe, (l & 48) + r * 4 + t);
                unsafeAtomicAdd(&pooled[(size_t)sr_[r] * 64 + t * 16 + c], a * aVe[t][r]);
            }

        // ---- node attention scores ----
        f32x4 aWe[4];
#pragma unroll
        for (int t = 0; t < 4; ++t) aWe[t] = zero4();
#pragma unroll
        for (int t = 0; t < 4; ++t) {
            const u16t* b0 = wt + (t * 16 + c) * 72;
            aWe[t] = MFMA(A0, *(const bf16x8*)(b0 + q * 8), aWe[t]);
            aWe[t] = MFMA(A1, *(const bf16x8*)(b0 + 32 + q * 8), aWe[t]);
        }
        float pn[16];
#pragma unroll
        for (int r = 0; r < 4; ++r)
#pragma unroll
            for (int t = 0; t < 4; ++t) {
                int col = t * 16 + c;
                float qg = b2f((short)qn[(size_t)tg_[r] * 64 + col]);
                float kg = b2f((short)kn[(size_t)sr_[r] * 64 + col]);
                pn[r * 4 + t] = qg * (kg + aWe[t][r]);
            }
        float exn = __expf(tree16(pn, l));
        unsafeAtomicAdd(&d_n[tgL * 4 + hL], exn);

        // ---- msg[tgt] += exn * vn[src] (feature layout, coalesced rows) ----
#pragma unroll
        for (int el = 0; el < 16; ++el) {
            int sE = __shfl(srL, el << 2);                    // const src lane -> readlane
            int tE = __shfl(tgL, el << 2);
            float a = __shfl(exn, (el << 2) + (l >> 4));      // head = l>>4's owner
            float vv = b2f((short)vn[(size_t)sE * 64 + l]);
            unsafeAtomicAdd(&msg[(size_t)tE * 64 + l], a * vv);
        }
    }
}

// ---------------- K6: node update GEMM: out(bf16) = (Ain * 1/(den+eps)) @ W (+ base) ----------------
__global__ __launch_bounds__(256) void k_node_update(
        const float* __restrict__ Ain, const float* __restrict__ den,
        const float* __restrict__ W, const float* __restrict__ base,
        u16t* __restrict__ out) {
    __shared__ __align__(16) u16t wt[64 * 72];
    for (int idx = threadIdx.x; idx < 4096; idx += 256) {
        int n = idx & 63, k = idx >> 6;
        wt[n * 72 + k] = (u16t)f2b(W[idx]);
    }
    __syncthreads();
    int l = threadIdx.x & 63, w = threadIdx.x >> 6;
    int q = l >> 4, c = l & 15;
    int r0 = blockIdx.x * 256 + w * 64;
    bf16x8 B[2][4];
#pragma unroll
    for (int ks = 0; ks < 2; ++ks)
#pragma unroll
        for (int t = 0; t < 4; ++t)
            B[ks][t] = *(const bf16x8*)(wt + (t * 16 + c) * 72 + ks * 32 + q * 8);
    for (int st = 0; st < 4; ++st) {
        int row = r0 + st * 16 + c;
        if (row >= NNODES) row = NNODES - 1;
        bf16x8 A[2];
#pragma unroll
        for (int ks = 0; ks < 2; ++ks) {
            // fragment covers cols ks*32 + q*8 .. +7 -> one head: ks*2 + (q>>1)
            float iv = 1.f / (den[row * 4 + ks * 2 + (q >> 1)] + 1e-9f);
            A[ks] = ld8fs(Ain + (size_t)row * 64 + ks * 32 + q * 8, iv);
        }
        f32x4 acc[4];
#pragma unroll
        for (int t = 0; t < 4; ++t) acc[t] = zero4();
#pragma unroll
        for (int t = 0; t < 4; ++t) {
            acc[t] = MFMA(A[0], B[0][t], acc[t]);
            acc[t] = MFMA(A[1], B[1][t], acc[t]);
        }
#pragma unroll
        for (int r = 0; r < 4; ++r) {
            int rw = r0 + st * 16 + q * 4 + r;
            if (rw < NNODES) {
#pragma unroll
                for (int t = 0; t < 4; ++t) {
                    int col = t * 16 + c;
                    float v = acc[t][r];
                    if (base) v += base[(size_t)rw * 64 + col];
                    out[(size_t)rw * 64 + col] = (u16t)f2b(v);
                }
            }
        }
    }
}

// ---------------- K7: classifier: gather+concat -> W1 -> GELU -> W2 -> out(f32) ----------------
__global__ __launch_bounds__(256) void k_classifier(
        const float* __restrict__ edges, const int* __restrict__ eidx,
        const u16t* __restrict__ newN, const u16t* __restrict__ pWo,
        const float* __restrict__ W1, const float* __restrict__ b1,
        const float* __restrict__ W2, const float* __restrict__ b2,
        float* __restrict__ out) {
    __shared__ __align__(16) u16t wt1[64 * 200];     // Wt1[n][k], n<64, k<192, stride 200
    __shared__ __align__(16) u16t wt2[48 * 72];      // Wt2[n][k], n<48 (pad 40->48 zeros), k<64
    __shared__ __align__(16) u16t hbuf[4][16 * 72];  // per-wave h tile, row stride 72
    for (int idx = threadIdx.x; idx < 192 * 64; idx += 256) {
        int n = idx & 63, k = idx >> 6;
        wt1[n * 200 + k] = (u16t)f2b(W1[idx]);
    }
    for (int idx = threadIdx.x; idx < 48 * 64; idx += 256) {
        int n = idx % 48, k = idx / 48;
        wt2[n * 72 + k] = (n < 40) ? (u16t)f2b(W2[k * 40 + n]) : (u16t)0;
    }
    __syncthreads();
    int l = threadIdx.x & 63, w = threadIdx.x >> 6;
    int q = l >> 4, c = l & 15;
    int e0 = blockIdx.x * 256 + w * 64;

    bf16x8 B1[6][4];
#pragma unroll
    for (int ks = 0; ks < 6; ++ks)
#pragma unroll
        for (int t = 0; t < 4; ++t)
            B1[ks][t] = *(const bf16x8*)(wt1 + (t * 16 + c) * 200 + ks * 32 + q * 8);
    bf16x8 B2[2][3];
#pragma unroll
    for (int ks = 0; ks < 2; ++ks)
#pragma unroll
        for (int t = 0; t < 3; ++t)
            B2[ks][t] = *(const bf16x8*)(wt2 + (t * 16 + c) * 72 + ks * 32 + q * 8);

    for (int st = 0; st < 4; ++st) {
        int em = e0 + st * 16 + c;
        int srm = eidx[em], tgm = eidx[NEDGES + em];
        bf16x8 A[6];
#pragma unroll
        for (int ks = 0; ks < 2; ++ks) {
            A[ks]     = *(const bf16x8*)(newN + (size_t)srm * 64 + ks * 32 + q * 8);
            A[2 + ks] = *(const bf16x8*)(newN + (size_t)tgm * 64 + ks * 32 + q * 8);
            const float* ep = edges + (size_t)em * 64 + ks * 32 + q * 8;
            float4 x0 = *(const float4*)ep;
            float4 x1 = *(const float4*)(ep + 4);
            bf16x8 y = *(const bf16x8*)(pWo + (size_t)srm * 64 + ks * 32 + q * 8);
            bf16x8 z;
            z[0] = f2b(x0.x + b2f(y[0])); z[1] = f2b(x0.y + b2f(y[1]));
            z[2] = f2b(x0.z + b2f(y[2])); z[3] = f2b(x0.w + b2f(y[3]));
            z[4] = f2b(x1.x + b2f(y[4])); z[5] = f2b(x1.y + b2f(y[5]));
            z[6] = f2b(x1.z + b2f(y[6])); z[7] = f2b(x1.w + b2f(y[7]));
            A[4 + ks] = z;
        }
        f32x4 acc1[4];
#pragma unroll
        for (int t = 0; t < 4; ++t) acc1[t] = zero4();
#pragma unroll
        for (int ks = 0; ks < 6; ++ks)
#pragma unroll
            for (int t = 0; t < 4; ++t)
                acc1[t] = MFMA(A[ks], B1[ks][t], acc1[t]);
        // bias + GELU -> hbuf (bf16, A-layout rows); hbuf is wave-private, no barrier needed
#pragma unroll
        for (int t = 0; t < 4; ++t) {
            float bb = b1[t * 16 + c];
#pragma unroll
            for (int r = 0; r < 4; ++r) {
                float x = acc1[t][r] + bb;
                hbuf[w][(q * 4 + r) * 72 + t * 16 + c] = (u16t)f2b(gelu_f(x));
            }
        }
        bf16x8 A2[2];
#pragma unroll
        for (int ks = 0; ks < 2; ++ks)
            A2[ks] = *(const bf16x8*)(&hbuf[w][c * 72 + ks * 32 + q * 8]);
        f32x4 acc2[3];
#pragma unroll
        for (int t = 0; t < 3; ++t) acc2[t] = zero4();
#pragma unroll
        for (int ks = 0; ks < 2; ++ks)
#pragma unroll
            for (int t = 0; t < 3; ++t)
                acc2[t] = MFMA(A2[ks], B2[ks][t], acc2[t]);
#pragma unroll
        for (int r = 0; r < 4; ++r) {
            int e = e0 + st * 16 + q * 4 + r;
#pragma unroll
            for (int t = 0; t < 3; ++t) {
                int col = t * 16 + c;
                if (col < 40)
                    out[(size_t)e * 40 + col] = acc2[t][r] + b2[col];
            }
        }
    }
}

extern "C" void kernel_launch(void* const* d_in, const int* in_sizes, int n_in,
                              void* d_out, int out_size, void* d_ws, size_t ws_size,
                              hipStream_t stream) {
    if (n_in < 17) return;
    const float* nodes = (const float*)d_in[0];
    const float* edges = (const float*)d_in[1];
    const int*   eidx  = (const int*)d_in[2];
    const float* Wq_n = (const float*)d_in[3];
    const float* Wk_n = (const float*)d_in[4];
    const float* We_n = (const float*)d_in[5];
    const float* Wv_n = (const float*)d_in[6];
    const float* Wo_n = (const float*)d_in[7];
    const float* Wq_e = (const float*)d_in[8];
    const float* Wk_e = (const float*)d_in[9];
    const float* Wn_e = (const float*)d_in[10];
    const float* Wv_e = (const float*)d_in[11];
    const float* Wo_e = (const float*)d_in[12];
    const float* W1   = (const float*)d_in[13];
    const float* b1   = (const float*)d_in[14];
    const float* W2   = (const float*)d_in[15];
    const float* b2   = (const float*)d_in[16];
    float* out = (float*)d_out;

    float* ws = (float*)d_ws;
    size_t o = 0;
    u16t* qn  = (u16t*)(ws + o); o += (size_t)NP * 32;
    u16t* kn  = (u16t*)(ws + o); o += (size_t)NP * 32;
    u16t* vn  = (u16t*)(ws + o); o += (size_t)NP * 32;
    u16t* nWn = (u16t*)(ws + o); o += (size_t)NP * 32;
    float* d_n = ws + o; o += (size_t)NP * 4;
    float* d_e = ws + o; o += (size_t)NP * 4;
    float* msg    = ws + o; o += (size_t)NP * 64;
    float* pooled = ws + o; o += (size_t)NP * 64;
    u16t* newN = (u16t*)(ws + o); o += (size_t)NP * 32;
    u16t* pWo  = (u16t*)(ws + o); o += (size_t)NP * 32;
    if (ws_size < o * sizeof(float)) return;  // not enough scratch: fail visibly

    k_init<<<12544, 256, 0, stream>>>(msg, pooled, d_n, d_e);
    k_node_proj<<<196, 256, 0, stream>>>(nodes, Wq_n, Wk_n, Wv_n, Wn_e, qn, kn, vn, nWn);
    k_edge_fused<<<3125, 256, 0, stream>>>(edges, eidx, We_n, Wq_e, Wk_e, Wv_e,
                                           qn, kn, nWn, vn, d_n, d_e, msg, pooled);
    k_node_update<<<196, 256, 0, stream>>>(msg, d_n, Wo_n, nodes, newN);
    k_node_update<<<196, 256, 0, stream>>>(pooled, d_e, Wo_e, nullptr, pWo);
    k_classifier<<<3125, 256, 0, stream>>>(edges, eidx, newN, pWo, W1, b1, W2, b2, out);
}

// Round 6
// 1055.374 us; speedup vs baseline: 1.0277x; 1.0277x over previous
//
#include <hip/hip_runtime.h>
#include <cstdint>
#include <cstddef>

typedef unsigned short u16t;
typedef __attribute__((ext_vector_type(8))) short bf16x8;  // 8 bf16 in 4 VGPRs
typedef __attribute__((ext_vector_type(4))) float f32x4;

#define NNODES 50000
#define NEDGES 800000
#define NP 50176   // 196 * 256, padded node rows

#define MFMA(a, b, c) __builtin_amdgcn_mfma_f32_16x16x32_bf16((a), (b), (c), 0, 0, 0)

__device__ inline float b2f(short s) {
    union { float f; unsigned int u; } c;
    c.u = ((unsigned int)(unsigned short)s) << 16;
    return c.f;
}
__device__ inline short f2b(float f) {
    union { float f; unsigned int u; } c; c.f = f;
    unsigned int u = c.u;
    unsigned int r = (u + 0x7FFFu + ((u >> 16) & 1u)) >> 16;  // RNE
    return (short)(unsigned short)r;
}
__device__ inline f32x4 zero4() { f32x4 z = {0.f, 0.f, 0.f, 0.f}; return z; }

// load 8 consecutive f32 and round to bf16x8 (A/B fragment builder)
__device__ inline bf16x8 ld8f(const float* p) {
    float4 a = *(const float4*)p;
    float4 b = *(const float4*)(p + 4);
    bf16x8 r;
    r[0] = f2b(a.x); r[1] = f2b(a.y); r[2] = f2b(a.z); r[3] = f2b(a.w);
    r[4] = f2b(b.x); r[5] = f2b(b.y); r[6] = f2b(b.z); r[7] = f2b(b.w);
    return r;
}

__device__ inline float gelu_f(float x) {
    float u = 0.7978845608028654f * (x + 0.044715f * x * x * x);
    float e = __expf(2.f * u);
    return 0.5f * x * (2.f - 2.f / (e + 1.f));
}

// multi-value tree reduce: a[v] per lane, v=0..15; returns (for lane l) the
// sum over its 16-lane group of a[l&15]. 15 shuffles per value set.
__device__ inline float tree16(float* a, int l) {
#pragma unroll
    for (int b = 0; b < 4; ++b) {
        const int m = 1 << b;
        const bool up = (l & m) != 0;
#pragma unroll
        for (int j = 0; j < (8 >> b); ++j) {
            float keep = up ? a[2 * j + 1] : a[2 * j];
            float send = up ? a[2 * j] : a[2 * j + 1];
            a[j] = keep + __shfl_xor(send, m);
        }
    }
    return a[0];
}

// inclusive wave scan (int)
__device__ inline int wscan_incl(int v) {
    int l = threadIdx.x & 63;
#pragma unroll
    for (int d = 1; d < 64; d <<= 1) {
        int t = __shfl_up(v, d);
        if (l >= d) v += t;
    }
    return v;
}

// ---------------- CSR build: zero, hist, scan(3), fill ----------------
// cnt layout: cnt[0..NP)   = in-degree by tgt  (node-attention list)
//             cnt[NP..2NP) = out-degree by src (edge-attention list)
__global__ void k_zero(int* __restrict__ cnt) {
    int i = blockIdx.x * 256 + threadIdx.x;
    cnt[i] = 0;   // grid exact: 392*256 = 2*NP
}

__global__ void k_hist(const int* __restrict__ eidx, int* __restrict__ cnt) {
    int e = blockIdx.x * 256 + threadIdx.x;   // grid exact: 3125*256 = NEDGES
    int sr = eidx[e], tg = eidx[NEDGES + e];
    atomicAdd(&cnt[tg], 1);
    atomicAdd(&cnt[NP + sr], 1);
}

__global__ void k_scan_blk(const int* __restrict__ cnt, int* __restrict__ incl,
                           int* __restrict__ tot) {
    __shared__ int wsum[4];
    int i = blockIdx.x * 256 + threadIdx.x;
    int v = cnt[i];
    int sc = wscan_incl(v);
    int w = threadIdx.x >> 6;
    if ((threadIdx.x & 63) == 63) wsum[w] = sc;
    __syncthreads();
    int off = 0;
    for (int k = 0; k < w; ++k) off += wsum[k];
    incl[i] = sc + off;
    if (threadIdx.x == 255) tot[blockIdx.x] = sc + off;
}

__global__ void k_scan_top(const int* __restrict__ tot, int* __restrict__ ttop) {
    __shared__ int wsum[8];
    int i = threadIdx.x;                      // 512 threads, 392 entries
    int v = (i < 392) ? tot[i] : 0;
    int sc = wscan_incl(v);
    int w = threadIdx.x >> 6;
    if ((threadIdx.x & 63) == 63) wsum[w] = sc;
    __syncthreads();
    int off = 0;
    for (int k = 0; k < w; ++k) off += wsum[k];
    if (i < 392) ttop[i] = sc + off - v;      // exclusive
}

__global__ void k_scan_add(const int* __restrict__ cnt, const int* __restrict__ incl,
                           const int* __restrict__ ttop, int* __restrict__ ofs,
                           int* __restrict__ cur) {
    int i = blockIdx.x * 256 + threadIdx.x;
    int v = incl[i] - cnt[i] + ttop[blockIdx.x];
    ofs[i] = v; cur[i] = v;
}

__global__ void k_fill(const int* __restrict__ eidx, int* __restrict__ cur,
                       int* __restrict__ perm) {
    int e = blockIdx.x * 256 + threadIdx.x;
    int sr = eidx[e], tg = eidx[NEDGES + e];
    perm[atomicAdd(&cur[tg], 1)] = e;         // tgt-list (first half)
    perm[atomicAdd(&cur[NP + sr], 1)] = e;    // src-list (second half)
}

// ---------------- K1: node projections (bf16 out): qn,kn,vn,nWn ----------------
__global__ __launch_bounds__(256) void k_node_proj(
        const float* __restrict__ nodes,
        const float* __restrict__ Wq, const float* __restrict__ Wk,
        const float* __restrict__ Wv, const float* __restrict__ Wn,
        u16t* __restrict__ qn, u16t* __restrict__ kn,
        u16t* __restrict__ vn, u16t* __restrict__ nWn) {
    __shared__ __align__(16) u16t wt[256 * 72];   // transposed: wt[n][k], stride 72
    {
        const float* Ws[4] = {Wq, Wk, Wv, Wn};
        for (int g = 0; g < 4; ++g) {
            const float* W = Ws[g];
            u16t* dst = wt + g * 64 * 72;
            for (int idx = threadIdx.x; idx < 4096; idx += 256) {
                int n = idx & 63, k = idx >> 6;
                dst[n * 72 + k] = (u16t)f2b(W[idx]);
            }
        }
    }
    __syncthreads();
    int l = threadIdx.x & 63, w = threadIdx.x >> 6;
    int q = l >> 4, c = l & 15;
    int r0 = blockIdx.x * 256 + w * 64;

    bf16x8 A[4][2];
#pragma unroll
    for (int st = 0; st < 4; ++st) {
        int row = r0 + st * 16 + c;
        if (row >= NNODES) row = NNODES - 1;
#pragma unroll
        for (int ks = 0; ks < 2; ++ks)
            A[st][ks] = ld8f(nodes + (size_t)row * 64 + ks * 32 + q * 8);
    }
    u16t* outs[4] = {qn, kn, vn, nWn};
    for (int cg = 0; cg < 4; ++cg) {
        bf16x8 B[2][4];
#pragma unroll
        for (int ks = 0; ks < 2; ++ks)
#pragma unroll
            for (int t = 0; t < 4; ++t)
                B[ks][t] = *(const bf16x8*)(wt + (cg * 64 + t * 16 + c) * 72 + ks * 32 + q * 8);
        float scale = (cg == 0) ? 0.25f : 1.0f;   // fold 1/sqrt(16) into q
        u16t* out = outs[cg];
#pragma unroll
        for (int st = 0; st < 4; ++st) {
            f32x4 acc[4];
#pragma unroll
            for (int t = 0; t < 4; ++t) acc[t] = zero4();
#pragma unroll
            for (int ks = 0; ks < 2; ++ks)
#pragma unroll
                for (int t = 0; t < 4; ++t)
                    acc[t] = MFMA(A[st][ks], B[ks][t], acc[t]);
#pragma unroll
            for (int r = 0; r < 4; ++r) {
                int row = r0 + st * 16 + q * 4 + r;
                if (row < NNODES) {
#pragma unroll
                    for (int t = 0; t < 4; ++t)
                        out[(size_t)row * 64 + t * 16 + c] = (u16t)f2b(acc[t][r] * scale);
                }
            }
        }
    }
}

// ---------------- K2: edge scores -> exp, store s_n/s_e (no atomics) ----------------
__global__ __launch_bounds__(256) void k_edge_scores(
        const float* __restrict__ edges, const int* __restrict__ eidx,
        const float* __restrict__ WeN, const float* __restrict__ WqE, const float* __restrict__ WkE,
        const u16t* __restrict__ qn, const u16t* __restrict__ kn, const u16t* __restrict__ nWn,
        float* __restrict__ s_n, float* __restrict__ s_e) {
    __shared__ __align__(16) u16t wt[192 * 72];
    for (int idx = threadIdx.x; idx < 4096; idx += 256) {
        int n = idx & 63, k = idx >> 6;
        wt[n * 72 + k]         = (u16t)f2b(WeN[idx]);
        wt[(64 + n) * 72 + k]  = (u16t)f2b(0.25f * WqE[idx]);  // fold 1/sqrt(16)
        wt[(128 + n) * 72 + k] = (u16t)f2b(WkE[idx]);
    }
    __syncthreads();
    int l = threadIdx.x & 63, w = threadIdx.x >> 6;
    int q = l >> 4, c = l & 15;
    int e0 = blockIdx.x * 256 + w * 64;

    for (int st = 0; st < 4; ++st) {
        int ebase = e0 + st * 16;
        int eA = ebase + c;
        bf16x8 A0 = ld8f(edges + (size_t)eA * 64 + q * 8);
        bf16x8 A1 = ld8f(edges + (size_t)eA * 64 + 32 + q * 8);

        int sr_[4], tg_[4];
#pragma unroll
        for (int r = 0; r < 4; ++r) {
            int e = ebase + q * 4 + r;
            sr_[r] = eidx[e];
            tg_[r] = eidx[NEDGES + e];
        }

        // ---- edge attention scores ----
        f32x4 aQe[4], aKe[4];
#pragma unroll
        for (int t = 0; t < 4; ++t) { aQe[t] = zero4(); aKe[t] = zero4(); }
#pragma unroll
        for (int t = 0; t < 4; ++t) {
            const u16t* b1 = wt + (64 + t * 16 + c) * 72;
            const u16t* b2 = wt + (128 + t * 16 + c) * 72;
            aQe[t] = MFMA(A0, *(const bf16x8*)(b1 + q * 8), aQe[t]);
            aQe[t] = MFMA(A1, *(const bf16x8*)(b1 + 32 + q * 8), aQe[t]);
            aKe[t] = MFMA(A0, *(const bf16x8*)(b2 + q * 8), aKe[t]);
            aKe[t] = MFMA(A1, *(const bf16x8*)(b2 + 32 + q * 8), aKe[t]);
        }
        float pe[16];
#pragma unroll
        for (int r = 0; r < 4; ++r)
#pragma unroll
            for (int t = 0; t < 4; ++t) {
                int col = t * 16 + c;
                float ng = b2f((short)nWn[(size_t)sr_[r] * 64 + col]);
                pe[r * 4 + t] = aQe[t][r] * (aKe[t][r] + ng);
            }
        s_e[(size_t)ebase * 4 + l] = __expf(tree16(pe, l));

        // ---- node attention scores ----
        f32x4 aWe[4];
#pragma unroll
        for (int t = 0; t < 4; ++t) aWe[t] = zero4();
#pragma unroll
        for (int t = 0; t < 4; ++t) {
            const u16t* b0 = wt + (t * 16 + c) * 72;
            aWe[t] = MFMA(A0, *(const bf16x8*)(b0 + q * 8), aWe[t]);
            aWe[t] = MFMA(A1, *(const bf16x8*)(b0 + 32 + q * 8), aWe[t]);
        }
        float pn[16];
#pragma unroll
        for (int r = 0; r < 4; ++r)
#pragma unroll
            for (int t = 0; t < 4; ++t) {
                int col = t * 16 + c;
                float qg = b2f((short)qn[(size_t)tg_[r] * 64 + col]);
                float kg = b2f((short)kn[(size_t)sr_[r] * 64 + col]);
                pn[r * 4 + t] = qg * (kg + aWe[t][r]);
            }
        s_n[(size_t)ebase * 4 + l] = __expf(tree16(pn, l));
    }
}

// ---------------- K3: CSR gather — one wave per node, atomic-free ----------------
// node phase: msg[n]    = sum_{e: tgt=n} s_n[e]*vn[src[e]] / den
// edge phase: pooled[n] = sum_{e: src=n} s_e[e]*(edges[e]@Wv_e) / den  (MFMA per 16-row chunk)
__global__ __launch_bounds__(256) void k_gather(
        const float* __restrict__ edges, const int* __restrict__ eidx,
        const float* __restrict__ WvE,
        const int* __restrict__ ofs, const int* __restrict__ cnt,
        const int* __restrict__ perm,
        const float* __restrict__ s_n, const float* __restrict__ s_e,
        const u16t* __restrict__ vn,
        float* __restrict__ msg, float* __restrict__ pooled) {
    __shared__ __align__(16) u16t wt[64 * 72];   // Wv_e^T
    for (int idx = threadIdx.x; idx < 4096; idx += 256) {
        int n = idx & 63, k = idx >> 6;
        wt[n * 72 + k] = (u16t)f2b(WvE[idx]);
    }
    __syncthreads();
    int l = threadIdx.x & 63;
    int q = l >> 4, c = l & 15;
    int gw = (blockIdx.x * 256 + (int)threadIdx.x) >> 6;   // node id (grid exact: 50000 waves)
    if (gw >= NNODES) return;

    // ---- node attention gather ----
    {
        int o0 = ofs[gw], n0 = cnt[gw];
        float acc = 0.f, den = 0.f;
        int e = (n0 > 0) ? perm[o0] : 0;
        for (int j = 0; j < n0; ++j) {
            int sr = eidx[e];
            int en = (j + 1 < n0) ? perm[o0 + j + 1] : 0;   // prefetch
            float a = s_n[(size_t)e * 4 + q];                // head = l>>4
            den += a;
            acc += a * b2f((short)vn[(size_t)sr * 64 + l]);
            e = en;
        }
        msg[(size_t)gw * 64 + l] = acc / (den + 1e-9f);
    }

    // ---- edge attention gather (MFMA over <=16-row chunks of the src-list) ----
    {
        int o1 = ofs[NP + gw], n1 = cnt[NP + gw];
        float part[4] = {0.f, 0.f, 0.f, 0.f};
        float dpart[4] = {0.f, 0.f, 0.f, 0.f};
        for (int j0 = 0; j0 < n1; j0 += 16) {
            int rem = n1 - j0;                        // >= 1
            int cc = (c < rem) ? c : (rem - 1);       // clamp A-row to valid edge
            int eC = perm[o1 + j0 + cc];
            bf16x8 A0 = ld8f(edges + (size_t)eC * 64 + q * 8);
            bf16x8 A1 = ld8f(edges + (size_t)eC * 64 + 32 + q * 8);
            f32x4 acc4[4];
#pragma unroll
            for (int t = 0; t < 4; ++t) acc4[t] = zero4();
#pragma unroll
            for (int t = 0; t < 4; ++t) {
                const u16t* bp = wt + (t * 16 + c) * 72;
                acc4[t] = MFMA(A0, *(const bf16x8*)(bp + q * 8), acc4[t]);
                acc4[t] = MFMA(A1, *(const bf16x8*)(bp + 32 + q * 8), acc4[t]);
            }
#pragma unroll
            for (int r = 0; r < 4; ++r) {
                int row = q * 4 + r;                  // accumulator row
                int eR = __shfl(eC, row);             // lane 'row' holds c==row
                float4 a4;
                if (row < rem) a4 = *(const float4*)(s_e + (size_t)eR * 4);
                else           { a4.x = 0.f; a4.y = 0.f; a4.z = 0.f; a4.w = 0.f; }
                float ar[4] = {a4.x, a4.y, a4.z, a4.w};
#pragma unroll
                for (int t = 0; t < 4; ++t) {
                    part[t] += ar[t] * acc4[t][r];
                    dpart[t] += ar[t];
                }
            }
        }
        // reduce across the 4 q-groups (rows are partitioned by q)
#pragma unroll
        for (int t = 0; t < 4; ++t) {
            part[t] += __shfl_xor(part[t], 16);
            part[t] += __shfl_xor(part[t], 32);
            dpart[t] += __shfl_xor(dpart[t], 16);
            dpart[t] += __shfl_xor(dpart[t], 32);
        }
        float pv = (q == 0) ? part[0] : (q == 1) ? part[1] : (q == 2) ? part[2] : part[3];
        float dv = (q == 0) ? dpart[0] : (q == 1) ? dpart[1] : (q == 2) ? dpart[2] : dpart[3];
        pooled[(size_t)gw * 64 + l] = pv / (dv + 1e-9f);
    }
}

// ---------------- K6: node update GEMM: out(bf16) = Ain @ W (+ base) ----------------
__global__ __launch_bounds__(256) void k_node_update(
        const float* __restrict__ Ain, const float* __restrict__ W,
        const float* __restrict__ base, u16t* __restrict__ out) {
    __shared__ __align__(16) u16t wt[64 * 72];
    for (int idx = threadIdx.x; idx < 4096; idx += 256) {
        int n = idx & 63, k = idx >> 6;
        wt[n * 72 + k] = (u16t)f2b(W[idx]);
    }
    __syncthreads();
    int l = threadIdx.x & 63, w = threadIdx.x >> 6;
    int q = l >> 4, c = l & 15;
    int r0 = blockIdx.x * 256 + w * 64;
    bf16x8 B[2][4];
#pragma unroll
    for (int ks = 0; ks < 2; ++ks)
#pragma unroll
        for (int t = 0; t < 4; ++t)
            B[ks][t] = *(const bf16x8*)(wt + (t * 16 + c) * 72 + ks * 32 + q * 8);
    for (int st = 0; st < 4; ++st) {
        int row = r0 + st * 16 + c;
        if (row >= NNODES) row = NNODES - 1;
        bf16x8 A[2];
#pragma unroll
        for (int ks = 0; ks < 2; ++ks)
            A[ks] = ld8f(Ain + (size_t)row * 64 + ks * 32 + q * 8);
        f32x4 acc[4];
#pragma unroll
        for (int t = 0; t < 4; ++t) acc[t] = zero4();
#pragma unroll
        for (int t = 0; t < 4; ++t) {
            acc[t] = MFMA(A[0], B[0][t], acc[t]);
            acc[t] = MFMA(A[1], B[1][t], acc[t]);
        }
#pragma unroll
        for (int r = 0; r < 4; ++r) {
            int rw = r0 + st * 16 + q * 4 + r;
            if (rw < NNODES) {
#pragma unroll
                for (int t = 0; t < 4; ++t) {
                    int col = t * 16 + c;
                    float v = acc[t][r];
                    if (base) v += base[(size_t)rw * 64 + col];
                    out[(size_t)rw * 64 + col] = (u16t)f2b(v);
                }
            }
        }
    }
}

// ---------------- K7: classifier: gather+concat -> W1 -> GELU -> W2 -> out(f32) ----------------
__global__ __launch_bounds__(256) void k_classifier(
        const float* __restrict__ edges, const int* __restrict__ eidx,
        const u16t* __restrict__ newN, const u16t* __restrict__ pWo,
        const float* __restrict__ W1, const float* __restrict__ b1,
        const float* __restrict__ W2, const float* __restrict__ b2,
        float* __restrict__ out) {
    __shared__ __align__(16) u16t wt1[64 * 200];     // Wt1[n][k], n<64, k<192, stride 200
    __shared__ __align__(16) u16t wt2[48 * 72];      // Wt2[n][k], n<48 (pad 40->48 zeros), k<64
    __shared__ __align__(16) u16t hbuf[4][16 * 72];  // per-wave h tile, row stride 72
    for (int idx = threadIdx.x; idx < 192 * 64; idx += 256) {
        int n = idx & 63, k = idx >> 6;
        wt1[n * 200 + k] = (u16t)f2b(W1[idx]);
    }
    for (int idx = threadIdx.x; idx < 48 * 64; idx += 256) {
        int n = idx % 48, k = idx / 48;
        wt2[n * 72 + k] = (n < 40) ? (u16t)f2b(W2[k * 40 + n]) : (u16t)0;
    }
    __syncthreads();
    int l = threadIdx.x & 63, w = threadIdx.x >> 6;
    int q = l >> 4, c = l & 15;
    int e0 = blockIdx.x * 256 + w * 64;

    bf16x8 B1[6][4];
#pragma unroll
    for (int ks = 0; ks < 6; ++ks)
#pragma unroll
        for (int t = 0; t < 4; ++t)
            B1[ks][t] = *(const bf16x8*)(wt1 + (t * 16 + c) * 200 + ks * 32 + q * 8);
    bf16x8 B2[2][3];
#pragma unroll
    for (int ks = 0; ks < 2; ++ks)
#pragma unroll
        for (int t = 0; t < 3; ++t)
            B2[ks][t] = *(const bf16x8*)(wt2 + (t * 16 + c) * 72 + ks * 32 + q * 8);

    for (int st = 0; st < 4; ++st) {
        int em = e0 + st * 16 + c;
        int srm = eidx[em], tgm = eidx[NEDGES + em];
        bf16x8 A[6];
#pragma unroll
        for (int ks = 0; ks < 2; ++ks) {
            A[ks]     = *(const bf16x8*)(newN + (size_t)srm * 64 + ks * 32 + q * 8);
            A[2 + ks] = *(const bf16x8*)(newN + (size_t)tgm * 64 + ks * 32 + q * 8);
            const float* ep = edges + (size_t)em * 64 + ks * 32 + q * 8;
            float4 x0 = *(const float4*)ep;
            float4 x1 = *(const float4*)(ep + 4);
            bf16x8 y = *(const bf16x8*)(pWo + (size_t)srm * 64 + ks * 32 + q * 8);
            bf16x8 z;
            z[0] = f2b(x0.x + b2f(y[0])); z[1] = f2b(x0.y + b2f(y[1]));
            z[2] = f2b(x0.z + b2f(y[2])); z[3] = f2b(x0.w + b2f(y[3]));
            z[4] = f2b(x1.x + b2f(y[4])); z[5] = f2b(x1.y + b2f(y[5]));
            z[6] = f2b(x1.z + b2f(y[6])); z[7] = f2b(x1.w + b2f(y[7]));
            A[4 + ks] = z;
        }
        f32x4 acc1[4];
#pragma unroll
        for (int t = 0; t < 4; ++t) acc1[t] = zero4();
#pragma unroll
        for (int ks = 0; ks < 6; ++ks)
#pragma unroll
            for (int t = 0; t < 4; ++t)
                acc1[t] = MFMA(A[ks], B1[ks][t], acc1[t]);
        // bias + GELU -> hbuf (bf16, A-layout rows); hbuf is wave-private, no barrier needed
#pragma unroll
        for (int t = 0; t < 4; ++t) {
            float bb = b1[t * 16 + c];
#pragma unroll
            for (int r = 0; r < 4; ++r) {
                float x = acc1[t][r] + bb;
                hbuf[w][(q * 4 + r) * 72 + t * 16 + c] = (u16t)f2b(gelu_f(x));
            }
        }
        bf16x8 A2[2];
#pragma unroll
        for (int ks = 0; ks < 2; ++ks)
            A2[ks] = *(const bf16x8*)(&hbuf[w][c * 72 + ks * 32 + q * 8]);
        f32x4 acc2[3];
#pragma unroll
        for (int t = 0; t < 3; ++t) acc2[t] = zero4();
#pragma unroll
        for (int ks = 0; ks < 2; ++ks)
#pragma unroll
            for (int t = 0; t < 3; ++t)
                acc2[t] = MFMA(A2[ks], B2[ks][t], acc2[t]);
#pragma unroll
        for (int r = 0; r < 4; ++r) {
            int e = e0 + st * 16 + q * 4 + r;
#pragma unroll
            for (int t = 0; t < 3; ++t) {
                int col = t * 16 + c;
                if (col < 40)
                    out[(size_t)e * 40 + col] = acc2[t][r] + b2[col];
            }
        }
    }
}

extern "C" void kernel_launch(void* const* d_in, const int* in_sizes, int n_in,
                              void* d_out, int out_size, void* d_ws, size_t ws_size,
                              hipStream_t stream) {
    if (n_in < 17) return;
    const float* nodes = (const float*)d_in[0];
    const float* edges = (const float*)d_in[1];
    const int*   eidx  = (const int*)d_in[2];
    const float* Wq_n = (const float*)d_in[3];
    const float* Wk_n = (const float*)d_in[4];
    const float* We_n = (const float*)d_in[5];
    const float* Wv_n = (const float*)d_in[6];
    const float* Wo_n = (const float*)d_in[7];
    const float* Wq_e = (const float*)d_in[8];
    const float* Wk_e = (const float*)d_in[9];
    const float* Wn_e = (const float*)d_in[10];
    const float* Wv_e = (const float*)d_in[11];
    const float* Wo_e = (const float*)d_in[12];
    const float* W1   = (const float*)d_in[13];
    const float* b1   = (const float*)d_in[14];
    const float* W2   = (const float*)d_in[15];
    const float* b2   = (const float*)d_in[16];
    float* out = (float*)d_out;

    float* ws = (float*)d_ws;
    size_t o = 0;
    u16t* qn  = (u16t*)(ws + o); o += (size_t)NP * 32;
    u16t* kn  = (u16t*)(ws + o); o += (size_t)NP * 32;
    u16t* vn  = (u16t*)(ws + o); o += (size_t)NP * 32;
    u16t* nWn = (u16t*)(ws + o); o += (size_t)NP * 32;
    float* s_n = ws + o; o += (size_t)NEDGES * 4;
    float* s_e = ws + o; o += (size_t)NEDGES * 4;
    float* msg    = ws + o; o += (size_t)NP * 64;
    float* pooled = ws + o; o += (size_t)NP * 64;
    u16t* newN = (u16t*)(ws + o); o += (size_t)NP * 32;
    u16t* pWo  = (u16t*)(ws + o); o += (size_t)NP * 32;
    int* cnt  = (int*)(ws + o); o += (size_t)2 * NP;
    int* incl = (int*)(ws + o); o += (size_t)2 * NP;
    int* ofs  = (int*)(ws + o); o += (size_t)2 * NP;
    int* cur  = (int*)(ws + o); o += (size_t)2 * NP;
    int* tot  = (int*)(ws + o); o += 512;
    int* ttop = (int*)(ws + o); o += 512;
    int* perm = (int*)(ws + o); o += (size_t)2 * NEDGES;
    if (ws_size < o * sizeof(float)) return;  // not enough scratch: fail visibly

    // CSR build
    k_zero<<<392, 256, 0, stream>>>(cnt);
    k_hist<<<3125, 256, 0, stream>>>(eidx, cnt);
    k_scan_blk<<<392, 256, 0, stream>>>(cnt, incl, tot);
    k_scan_top<<<1, 512, 0, stream>>>(tot, ttop);
    k_scan_add<<<392, 256, 0, stream>>>(cnt, incl, ttop, ofs, cur);
    k_fill<<<3125, 256, 0, stream>>>(eidx, cur, perm);
    // main pipeline
    k_node_proj<<<196, 256, 0, stream>>>(nodes, Wq_n, Wk_n, Wv_n, Wn_e, qn, kn, vn, nWn);
    k_edge_scores<<<3125, 256, 0, stream>>>(edges, eidx, We_n, Wq_e, Wk_e,
                                            qn, kn, nWn, s_n, s_e);
    k_gather<<<12500, 256, 0, stream>>>(edges, eidx, Wv_e, ofs, cnt, perm,
                                        s_n, s_e, vn, msg, pooled);
    k_node_update<<<196, 256, 0, stream>>>(msg, Wo_n, nodes, newN);
    k_node_update<<<196, 256, 0, stream>>>(pooled, Wo_e, nullptr, pWo);
    k_classifier<<<3125, 256, 0, stream>>>(edges, eidx, newN, pWo, W1, b1, W2, b2, out);
}

// Round 10
// 901.942 us; speedup vs baseline: 1.2025x; 1.1701x over previous
//
#include <hip/hip_runtime.h>
#include <cstdint>
#include <cstddef>

typedef unsigned short u16t;
typedef __attribute__((ext_vector_type(8))) short bf16x8;  // 8 bf16 in 4 VGPRs
typedef __attribute__((ext_vector_type(4))) float f32x4;

#define NNODES 50000
#define NEDGES 800000
#define NP 50176   // 196 * 256, padded node rows

#define MFMA(a, b, c) __builtin_amdgcn_mfma_f32_16x16x32_bf16((a), (b), (c), 0, 0, 0)

__device__ inline float b2f(short s) {
    union { float f; unsigned int u; } c;
    c.u = ((unsigned int)(unsigned short)s) << 16;
    return c.f;
}
__device__ inline short f2b(float f) {
    union { float f; unsigned int u; } c; c.f = f;
    unsigned int u = c.u;
    unsigned int r = (u + 0x7FFFu + ((u >> 16) & 1u)) >> 16;  // RNE
    return (short)(unsigned short)r;
}
__device__ inline f32x4 zero4() { f32x4 z = {0.f, 0.f, 0.f, 0.f}; return z; }

// load 8 consecutive f32 and round to bf16x8 (A/B fragment builder)
__device__ inline bf16x8 ld8f(const float* p) {
    float4 a = *(const float4*)p;
    float4 b = *(const float4*)(p + 4);
    bf16x8 r;
    r[0] = f2b(a.x); r[1] = f2b(a.y); r[2] = f2b(a.z); r[3] = f2b(a.w);
    r[4] = f2b(b.x); r[5] = f2b(b.y); r[6] = f2b(b.z); r[7] = f2b(b.w);
    return r;
}

__device__ inline float gelu_f(float x) {
    float u = 0.7978845608028654f * (x + 0.044715f * x * x * x);
    float e = __expf(2.f * u);
    return 0.5f * x * (2.f - 2.f / (e + 1.f));
}

// multi-value tree reduce: a[v] per lane, v=0..15; returns (for lane l) the
// sum over its 16-lane group of a[l&15]. 15 shuffles per value set.
__device__ inline float tree16(float* a, int l) {
#pragma unroll
    for (int b = 0; b < 4; ++b) {
        const int m = 1 << b;
        const bool up = (l & m) != 0;
#pragma unroll
        for (int j = 0; j < (8 >> b); ++j) {
            float keep = up ? a[2 * j + 1] : a[2 * j];
            float send = up ? a[2 * j] : a[2 * j + 1];
            a[j] = keep + __shfl_xor(send, m);
        }
    }
    return a[0];
}

// inclusive wave scan (int)
__device__ inline int wscan_incl(int v) {
    int l = threadIdx.x & 63;
#pragma unroll
    for (int d = 1; d < 64; d <<= 1) {
        int t = __shfl_up(v, d);
        if (l >= d) v += t;
    }
    return v;
}

// ---------------- CSR build: zero, hist, scan(3), fill ----------------
__global__ void k_zero(int* __restrict__ cnt) {
    int i = blockIdx.x * 256 + threadIdx.x;
    cnt[i] = 0;   // grid exact: 392*256 = 2*NP
}

__global__ void k_hist(const int* __restrict__ eidx, int* __restrict__ cnt) {
    int e = blockIdx.x * 256 + threadIdx.x;   // grid exact: 3125*256 = NEDGES
    int sr = eidx[e], tg = eidx[NEDGES + e];
    atomicAdd(&cnt[tg], 1);
    atomicAdd(&cnt[NP + sr], 1);
}

__global__ void k_scan_blk(const int* __restrict__ cnt, int* __restrict__ incl,
                           int* __restrict__ tot) {
    __shared__ int wsumS[4];
    int i = blockIdx.x * 256 + threadIdx.x;
    int v = cnt[i];
    int sc = wscan_incl(v);
    int w = threadIdx.x >> 6;
    if ((threadIdx.x & 63) == 63) wsumS[w] = sc;
    __syncthreads();
    int off = 0;
    for (int k = 0; k < w; ++k) off += wsumS[k];
    incl[i] = sc + off;
    if (threadIdx.x == 255) tot[blockIdx.x] = sc + off;
}

__global__ void k_scan_top(const int* __restrict__ tot, int* __restrict__ ttop) {
    __shared__ int wsumS[8];
    int i = threadIdx.x;                      // 512 threads, 392 entries
    int v = (i < 392) ? tot[i] : 0;
    int sc = wscan_incl(v);
    int w = threadIdx.x >> 6;
    if ((threadIdx.x & 63) == 63) wsumS[w] = sc;
    __syncthreads();
    int off = 0;
    for (int k = 0; k < w; ++k) off += wsumS[k];
    if (i < 392) ttop[i] = sc + off - v;      // exclusive
}

__global__ void k_scan_add(const int* __restrict__ cnt, const int* __restrict__ incl,
                           const int* __restrict__ ttop, int* __restrict__ ofs,
                           int* __restrict__ cur) {
    int i = blockIdx.x * 256 + threadIdx.x;
    int v = incl[i] - cnt[i] + ttop[blockIdx.x];
    ofs[i] = v; cur[i] = v;
}

__global__ void k_fill(const int* __restrict__ eidx, int* __restrict__ cur,
                       int* __restrict__ perm) {
    int e = blockIdx.x * 256 + threadIdx.x;
    int sr = eidx[e], tg = eidx[NEDGES + e];
    perm[atomicAdd(&cur[tg], 1)] = e;         // tgt-list (first half)
    perm[atomicAdd(&cur[NP + sr], 1)] = e;    // src-list (second half)
}

// ---------------- Wbig[h*64+k][d] = sum_{c in head h} Wv[k][c] * Wo[c][d] ----------------
// Exact fold of per-head weighting: pooled@Wo_e == wsum4_flat(N x 256) @ Wbig(256 x 64)
__global__ void k_wbig(const float* __restrict__ Wv, const float* __restrict__ Wo,
                       float* __restrict__ Wbig) {
    int i = blockIdx.x * 256 + threadIdx.x;   // grid 64*256 = 16384
    int row = i >> 6, d = i & 63;
    int h = row >> 6, k = row & 63;
    float s = 0.f;
#pragma unroll
    for (int j = 0; j < 16; ++j)
        s += Wv[k * 64 + h * 16 + j] * Wo[(h * 16 + j) * 64 + d];
    Wbig[i] = s;
}

// ---------------- K1: node projections (bf16 out): qn,kn,vn,nWn ----------------
__global__ __launch_bounds__(256) void k_node_proj(
        const float* __restrict__ nodes,
        const float* __restrict__ Wq, const float* __restrict__ Wk,
        const float* __restrict__ Wv, const float* __restrict__ Wn,
        u16t* __restrict__ qn, u16t* __restrict__ kn,
        u16t* __restrict__ vn, u16t* __restrict__ nWn) {
    __shared__ __align__(16) u16t wt[256 * 72];   // transposed: wt[n][k], stride 72
    {
        const float* Ws[4] = {Wq, Wk, Wv, Wn};
        for (int g = 0; g < 4; ++g) {
            const float* W = Ws[g];
            u16t* dst = wt + g * 64 * 72;
            for (int idx = threadIdx.x; idx < 4096; idx += 256) {
                int n = idx & 63, k = idx >> 6;
                dst[n * 72 + k] = (u16t)f2b(W[idx]);
            }
        }
    }
    __syncthreads();
    int l = threadIdx.x & 63, w = threadIdx.x >> 6;
    int q = l >> 4, c = l & 15;
    int r0 = blockIdx.x * 256 + w * 64;

    bf16x8 A[4][2];
#pragma unroll
    for (int st = 0; st < 4; ++st) {
        int row = r0 + st * 16 + c;
        if (row >= NNODES) row = NNODES - 1;
#pragma unroll
        for (int ks = 0; ks < 2; ++ks)
            A[st][ks] = ld8f(nodes + (size_t)row * 64 + ks * 32 + q * 8);
    }
    u16t* outs[4] = {qn, kn, vn, nWn};
    for (int cg = 0; cg < 4; ++cg) {
        bf16x8 B[2][4];
#pragma unroll
        for (int ks = 0; ks < 2; ++ks)
#pragma unroll
            for (int t = 0; t < 4; ++t)
                B[ks][t] = *(const bf16x8*)(wt + (cg * 64 + t * 16 + c) * 72 + ks * 32 + q * 8);
        float scale = (cg == 0) ? 0.25f : 1.0f;   // fold 1/sqrt(16) into q
        u16t* out = outs[cg];
#pragma unroll
        for (int st = 0; st < 4; ++st) {
            f32x4 acc[4];
#pragma unroll
            for (int t = 0; t < 4; ++t) acc[t] = zero4();
#pragma unroll
            for (int ks = 0; ks < 2; ++ks)
#pragma unroll
                for (int t = 0; t < 4; ++t)
                    acc[t] = MFMA(A[st][ks], B[ks][t], acc[t]);
#pragma unroll
            for (int r = 0; r < 4; ++r) {
                int row = r0 + st * 16 + q * 4 + r;
                if (row < NNODES) {
#pragma unroll
                    for (int t = 0; t < 4; ++t)
                        out[(size_t)row * 64 + t * 16 + c] = (u16t)f2b(acc[t][r] * scale);
                }
            }
        }
    }
}

// ---------------- K2: edge scores -> exp, store s_n/s_e (no atomics) ----------------
__global__ __launch_bounds__(256) void k_edge_scores(
        const float* __restrict__ edges, const int* __restrict__ eidx,
        const float* __restrict__ WeN, const float* __restrict__ WqE, const float* __restrict__ WkE,
        const u16t* __restrict__ qn, const u16t* __restrict__ kn, const u16t* __restrict__ nWn,
        float* __restrict__ s_n, float* __restrict__ s_e) {
    __shared__ __align__(16) u16t wt[192 * 72];
    for (int idx = threadIdx.x; idx < 4096; idx += 256) {
        int n = idx & 63, k = idx >> 6;
        wt[n * 72 + k]         = (u16t)f2b(WeN[idx]);
        wt[(64 + n) * 72 + k]  = (u16t)f2b(0.25f * WqE[idx]);  // fold 1/sqrt(16)
        wt[(128 + n) * 72 + k] = (u16t)f2b(WkE[idx]);
    }
    __syncthreads();
    int l = threadIdx.x & 63, w = threadIdx.x >> 6;
    int q = l >> 4, c = l & 15;
    int e0 = blockIdx.x * 256 + w * 64;

    for (int st = 0; st < 4; ++st) {
        int ebase = e0 + st * 16;
        int eA = ebase + c;
        bf16x8 A0 = ld8f(edges + (size_t)eA * 64 + q * 8);
        bf16x8 A1 = ld8f(edges + (size_t)eA * 64 + 32 + q * 8);

        int sr_[4], tg_[4];
#pragma unroll
        for (int r = 0; r < 4; ++r) {
            int e = ebase + q * 4 + r;
            sr_[r] = eidx[e];
            tg_[r] = eidx[NEDGES + e];
        }

        // ---- edge attention scores ----
        f32x4 aQe[4], aKe[4];
#pragma unroll
        for (int t = 0; t < 4; ++t) { aQe[t] = zero4(); aKe[t] = zero4(); }
#pragma unroll
        for (int t = 0; t < 4; ++t) {
            const u16t* b1 = wt + (64 + t * 16 + c) * 72;
            const u16t* b2 = wt + (128 + t * 16 + c) * 72;
            aQe[t] = MFMA(A0, *(const bf16x8*)(b1 + q * 8), aQe[t]);
            aQe[t] = MFMA(A1, *(const bf16x8*)(b1 + 32 + q * 8), aQe[t]);
            aKe[t] = MFMA(A0, *(const bf16x8*)(b2 + q * 8), aKe[t]);
            aKe[t] = MFMA(A1, *(const bf16x8*)(b2 + 32 + q * 8), aKe[t]);
        }
        float pe[16];
#pragma unroll
        for (int r = 0; r < 4; ++r)
#pragma unroll
            for (int t = 0; t < 4; ++t) {
                int col = t * 16 + c;
                float ng = b2f((short)nWn[(size_t)sr_[r] * 64 + col]);
                pe[r * 4 + t] = aQe[t][r] * (aKe[t][r] + ng);
            }
        s_e[(size_t)ebase * 4 + l] = __expf(tree16(pe, l));

        // ---- node attention scores ----
        f32x4 aWe[4];
#pragma unroll
        for (int t = 0; t < 4; ++t) aWe[t] = zero4();
#pragma unroll
        for (int t = 0; t < 4; ++t) {
            const u16t* b0 = wt + (t * 16 + c) * 72;
            aWe[t] = MFMA(A0, *(const bf16x8*)(b0 + q * 8), aWe[t]);
            aWe[t] = MFMA(A1, *(const bf16x8*)(b0 + 32 + q * 8), aWe[t]);
        }
        float pn[16];
#pragma unroll
        for (int r = 0; r < 4; ++r)
#pragma unroll
            for (int t = 0; t < 4; ++t) {
                int col = t * 16 + c;
                float qg = b2f((short)qn[(size_t)tg_[r] * 64 + col]);
                float kg = b2f((short)kn[(size_t)sr_[r] * 64 + col]);
                pn[r * 4 + t] = qg * (kg + aWe[t][r]);
            }
        s_n[(size_t)ebase * 4 + l] = __expf(tree16(pn, l));
    }
}

// ---------------- K3a: node-attention gather (batched, atomic-free) ----------------
// msg[n] = (sum_{e: tgt=n} s_n[e,h(l)] * vn[src[e]][l]) / den[h(l)]
__global__ __launch_bounds__(256) void k_gatherA(
        const int* __restrict__ eidx,
        const int* __restrict__ ofs, const int* __restrict__ cnt,
        const int* __restrict__ perm, const float* __restrict__ s_n,
        const u16t* __restrict__ vn, float* __restrict__ msg) {
    __shared__ float sw[4][64 * 4];   // per-wave staged weights (float4 per edge)
    __shared__ int   sx[4][64];       // per-wave staged src ids
    int l = threadIdx.x & 63, w = threadIdx.x >> 6;
    int q = l >> 4;
    int gw = (blockIdx.x * 256 + (int)threadIdx.x) >> 6;   // node id
    if (gw >= NNODES) return;

    int o0 = ofs[gw], n0 = cnt[gw];
    float acc = 0.f, den = 0.f;
    for (int j0 = 0; j0 < n0; j0 += 64) {
        int m = n0 - j0; if (m > 64) m = 64;
        if (l < m) {
            int e = perm[o0 + j0 + l];
            sx[w][l] = eidx[e];                               // src node
            *(float4*)&sw[w][l * 4] = *(const float4*)(s_n + (size_t)e * 4);
        }
        // wave-private LDS staging: same-wave in-order, no barrier (hbuf idiom)
        int jj = 0;
        for (; jj + 3 < m; jj += 4) {
#pragma unroll
            for (int u = 0; u < 4; ++u) {
                float a = sw[w][(jj + u) * 4 + q];
                int sr = sx[w][jj + u];
                den += a;
                acc += a * b2f((short)vn[(size_t)sr * 64 + l]);
            }
        }
        for (; jj < m; ++jj) {
            float a = sw[w][jj * 4 + q];
            int sr = sx[w][jj];
            den += a;
            acc += a * b2f((short)vn[(size_t)sr * 64 + l]);
        }
    }
    msg[(size_t)gw * 64 + l] = acc / (den + 1e-9f);
}

// ---------------- K3b: edge-attention gather: per-head weighted raw-edge sums ----------------
// wsum4[n][h*64+l] = (sum_{e: src=n} s_e[e,h] * edges[e][l]) / den[h]   (bf16 out, N x 256)
__global__ __launch_bounds__(256) void k_gatherB(
        const float* __restrict__ edges,
        const int* __restrict__ ofs, const int* __restrict__ cnt,
        const int* __restrict__ perm, const float* __restrict__ s_e,
        u16t* __restrict__ wsum4) {
    __shared__ float sw[4][64 * 4];
    __shared__ int   sx[4][64];
    int l = threadIdx.x & 63, w = threadIdx.x >> 6;
    int gw = (blockIdx.x * 256 + (int)threadIdx.x) >> 6;   // node id
    if (gw >= NNODES) return;

    int o1 = ofs[NP + gw], n1 = cnt[NP + gw];
    float a0s = 0.f, a1s = 0.f, a2s = 0.f, a3s = 0.f;        // per-head dens
    float c0 = 0.f, c1 = 0.f, c2 = 0.f, c3 = 0.f;            // per-head sums
    for (int j0 = 0; j0 < n1; j0 += 64) {
        int m = n1 - j0; if (m > 64) m = 64;
        if (l < m) {
            int e = perm[o1 + j0 + l];
            sx[w][l] = e;
            *(float4*)&sw[w][l * 4] = *(const float4*)(s_e + (size_t)e * 4);
        }
#pragma unroll 4
        for (int jj = 0; jj < m; ++jj) {
            int e = sx[w][jj];
            float x = edges[(size_t)e * 64 + l];              // coalesced 256B row
            float a0 = sw[w][jj * 4 + 0], a1 = sw[w][jj * 4 + 1];
            float a2 = sw[w][jj * 4 + 2], a3 = sw[w][jj * 4 + 3];
            a0s += a0; a1s += a1; a2s += a2; a3s += a3;
            c0 += a0 * x; c1 += a1 * x; c2 += a2 * x; c3 += a3 * x;
        }
    }
    size_t base = (size_t)gw * 256 + l;
    wsum4[base]       = (u16t)f2b(c0 / (a0s + 1e-9f));
    wsum4[base + 64]  = (u16t)f2b(c1 / (a1s + 1e-9f));
    wsum4[base + 128] = (u16t)f2b(c2 / (a2s + 1e-9f));
    wsum4[base + 192] = (u16t)f2b(c3 / (a3s + 1e-9f));
}

// ---------------- K6: node update GEMM: out(bf16) = Ain(f32) @ W (+ base) ----------------
__global__ __launch_bounds__(256) void k_node_update(
        const float* __restrict__ Ain, const float* __restrict__ W,
        const float* __restrict__ base, u16t* __restrict__ out) {
    __shared__ __align__(16) u16t wt[64 * 72];
    for (int idx = threadIdx.x; idx < 4096; idx += 256) {
        int n = idx & 63, k = idx >> 6;
        wt[n * 72 + k] = (u16t)f2b(W[idx]);
    }
    __syncthreads();
    int l = threadIdx.x & 63, w = threadIdx.x >> 6;
    int q = l >> 4, c = l & 15;
    int r0 = blockIdx.x * 256 + w * 64;
    bf16x8 B[2][4];
#pragma unroll
    for (int ks = 0; ks < 2; ++ks)
#pragma unroll
        for (int t = 0; t < 4; ++t)
            B[ks][t] = *(const bf16x8*)(wt + (t * 16 + c) * 72 + ks * 32 + q * 8);
    for (int st = 0; st < 4; ++st) {
        int row = r0 + st * 16 + c;
        if (row >= NNODES) row = NNODES - 1;
        bf16x8 A[2];
#pragma unroll
        for (int ks = 0; ks < 2; ++ks)
            A[ks] = ld8f(Ain + (size_t)row * 64 + ks * 32 + q * 8);
        f32x4 acc[4];
#pragma unroll
        for (int t = 0; t < 4; ++t) acc[t] = zero4();
#pragma unroll
        for (int t = 0; t < 4; ++t) {
            acc[t] = MFMA(A[0], B[0][t], acc[t]);
            acc[t] = MFMA(A[1], B[1][t], acc[t]);
        }
#pragma unroll
        for (int r = 0; r < 4; ++r) {
            int rw = r0 + st * 16 + q * 4 + r;
            if (rw < NNODES) {
#pragma unroll
                for (int t = 0; t < 4; ++t) {
                    int col = t * 16 + c;
                    float v = acc[t][r];
                    if (base) v += base[(size_t)rw * 64 + col];
                    out[(size_t)rw * 64 + col] = (u16t)f2b(v);
                }
            }
        }
    }
}

// ---------------- K6b: K=256 GEMM: pWo(bf16) = wsum4(bf16, N x 256) @ Wbig(256 x 64) ----------------
__global__ __launch_bounds__(256) void k_node_update256(
        const u16t* __restrict__ Ain, const float* __restrict__ W,
        u16t* __restrict__ out) {
    __shared__ __align__(16) u16t wt[64 * 264];   // wt[n][k], n<64, k<256, stride 264
    for (int idx = threadIdx.x; idx < 256 * 64; idx += 256) {
        int n = idx & 63, k = idx >> 6;
        wt[n * 264 + k] = (u16t)f2b(W[k * 64 + n]);
    }
    __syncthreads();
    int l = threadIdx.x & 63, w = threadIdx.x >> 6;
    int q = l >> 4, c = l & 15;
    int r0 = blockIdx.x * 256 + w * 64;
    for (int st = 0; st < 4; ++st) {
        int row = r0 + st * 16 + c;
        if (row >= NNODES) row = NNODES - 1;
        f32x4 acc[4];
#pragma unroll
        for (int t = 0; t < 4; ++t) acc[t] = zero4();
#pragma unroll
        for (int ks = 0; ks < 8; ++ks) {
            bf16x8 A = *(const bf16x8*)(Ain + (size_t)row * 256 + ks * 32 + q * 8);
#pragma unroll
            for (int t = 0; t < 4; ++t)
                acc[t] = MFMA(A, *(const bf16x8*)(wt + (t * 16 + c) * 264 + ks * 32 + q * 8), acc[t]);
        }
#pragma unroll
        for (int r = 0; r < 4; ++r) {
            int rw = r0 + st * 16 + q * 4 + r;
            if (rw < NNODES) {
#pragma unroll
                for (int t = 0; t < 4; ++t)
                    out[(size_t)rw * 64 + t * 16 + c] = (u16t)f2b(acc[t][r]);
            }
        }
    }
}

// ---------------- K7: classifier: gather+concat -> W1 -> GELU -> W2 -> out(f32) ----------------
__global__ __launch_bounds__(256) void k_classifier(
        const float* __restrict__ edges, const int* __restrict__ eidx,
        const u16t* __restrict__ newN, const u16t* __restrict__ pWo,
        const float* __restrict__ W1, const float* __restrict__ b1,
        const float* __restrict__ W2, const float* __restrict__ b2,
        float* __restrict__ out) {
    __shared__ __align__(16) u16t wt1[64 * 200];     // Wt1[n][k], n<64, k<192, stride 200
    __shared__ __align__(16) u16t wt2[48 * 72];      // Wt2[n][k], n<48 (pad 40->48 zeros), k<64
    __shared__ __align__(16) u16t hbuf[4][16 * 72];  // per-wave h tile, row stride 72
    for (int idx = threadIdx.x; idx < 192 * 64; idx += 256) {
        int n = idx & 63, k = idx >> 6;
        wt1[n * 200 + k] = (u16t)f2b(W1[idx]);
    }
    for (int idx = threadIdx.x; idx < 48 * 64; idx += 256) {
        int n = idx % 48, k = idx / 48;
        wt2[n * 72 + k] = (n < 40) ? (u16t)f2b(W2[k * 40 + n]) : (u16t)0;
    }
    __syncthreads();
    int l = threadIdx.x & 63, w = threadIdx.x >> 6;
    int q = l >> 4, c = l & 15;
    int e0 = blockIdx.x * 256 + w * 64;

    bf16x8 B1[6][4];
#pragma unroll
    for (int ks = 0; ks < 6; ++ks)
#pragma unroll
        for (int t = 0; t < 4; ++t)
            B1[ks][t] = *(const bf16x8*)(wt1 + (t * 16 + c) * 200 + ks * 32 + q * 8);
    bf16x8 B2[2][3];
#pragma unroll
    for (int ks = 0; ks < 2; ++ks)
#pragma unroll
        for (int t = 0; t < 3; ++t)
            B2[ks][t] = *(const bf16x8*)(wt2 + (t * 16 + c) * 72 + ks * 32 + q * 8);

    for (int st = 0; st < 4; ++st) {
        int em = e0 + st * 16 + c;
        int srm = eidx[em], tgm = eidx[NEDGES + em];
        bf16x8 A[6];
#pragma unroll
        for (int ks = 0; ks < 2; ++ks) {
            A[ks]     = *(const bf16x8*)(newN + (size_t)srm * 64 + ks * 32 + q * 8);
            A[2 + ks] = *(const bf16x8*)(newN + (size_t)tgm * 64 + ks * 32 + q * 8);
            const float* ep = edges + (size_t)em * 64 + ks * 32 + q * 8;
            float4 x0 = *(const float4*)ep;
            float4 x1 = *(const float4*)(ep + 4);
            bf16x8 y = *(const bf16x8*)(pWo + (size_t)srm * 64 + ks * 32 + q * 8);
            bf16x8 z;
            z[0] = f2b(x0.x + b2f(y[0])); z[1] = f2b(x0.y + b2f(y[1]));
            z[2] = f2b(x0.z + b2f(y[2])); z[3] = f2b(x0.w + b2f(y[3]));
            z[4] = f2b(x1.x + b2f(y[4])); z[5] = f2b(x1.y + b2f(y[5]));
            z[6] = f2b(x1.z + b2f(y[6])); z[7] = f2b(x1.w + b2f(y[7]));
            A[4 + ks] = z;
        }
        f32x4 acc1[4];
#pragma unroll
        for (int t = 0; t < 4; ++t) acc1[t] = zero4();
#pragma unroll
        for (int ks = 0; ks < 6; ++ks)
#pragma unroll
            for (int t = 0; t < 4; ++t)
                acc1[t] = MFMA(A[ks], B1[ks][t], acc1[t]);
        // bias + GELU -> hbuf (bf16, A-layout rows); hbuf is wave-private, no barrier needed
#pragma unroll
        for (int t = 0; t < 4; ++t) {
            float bb = b1[t * 16 + c];
#pragma unroll
            for (int r = 0; r < 4; ++r) {
                float x = acc1[t][r] + bb;
                hbuf[w][(q * 4 + r) * 72 + t * 16 + c] = (u16t)f2b(gelu_f(x));
            }
        }
        bf16x8 A2[2];
#pragma unroll
        for (int ks = 0; ks < 2; ++ks)
            A2[ks] = *(const bf16x8*)(&hbuf[w][c * 72 + ks * 32 + q * 8]);
        f32x4 acc2[3];
#pragma unroll
        for (int t = 0; t < 3; ++t) acc2[t] = zero4();
#pragma unroll
        for (int ks = 0; ks < 2; ++ks)
#pragma unroll
            for (int t = 0; t < 3; ++t)
                acc2[t] = MFMA(A2[ks], B2[ks][t], acc2[t]);
#pragma unroll
        for (int r = 0; r < 4; ++r) {
            int e = e0 + st * 16 + q * 4 + r;
#pragma unroll
            for (int t = 0; t < 3; ++t) {
                int col = t * 16 + c;
                if (col < 40)
                    out[(size_t)e * 40 + col] = acc2[t][r] + b2[col];
            }
        }
    }
}

extern "C" void kernel_launch(void* const* d_in, const int* in_sizes, int n_in,
                              void* d_out, int out_size, void* d_ws, size_t ws_size,
                              hipStream_t stream) {
    if (n_in < 17) return;
    const float* nodes = (const float*)d_in[0];
    const float* edges = (const float*)d_in[1];
    const int*   eidx  = (const int*)d_in[2];
    const float* Wq_n = (const float*)d_in[3];
    const float* Wk_n = (const float*)d_in[4];
    const float* We_n = (const float*)d_in[5];
    const float* Wv_n = (const float*)d_in[6];
    const float* Wo_n = (const float*)d_in[7];
    const float* Wq_e = (const float*)d_in[8];
    const float* Wk_e = (const float*)d_in[9];
    const float* Wn_e = (const float*)d_in[10];
    const float* Wv_e = (const float*)d_in[11];
    const float* Wo_e = (const float*)d_in[12];
    const float* W1   = (const float*)d_in[13];
    const float* b1   = (const float*)d_in[14];
    const float* W2   = (const float*)d_in[15];
    const float* b2   = (const float*)d_in[16];
    float* out = (float*)d_out;

    float* ws = (float*)d_ws;
    size_t o = 0;
    u16t* vn   = (u16t*)(ws + o); o += (size_t)NP * 32;
    float* s_e = ws + o; o += (size_t)NEDGES * 4;
    float* msg = ws + o; o += (size_t)NP * 64;
    u16t* newN = (u16t*)(ws + o); o += (size_t)NP * 32;
    u16t* pWo  = (u16t*)(ws + o); o += (size_t)NP * 32;
    float* Wbig = ws + o; o += 16384;
    int* cnt  = (int*)(ws + o); o += (size_t)2 * NP;
    int* ofs  = (int*)(ws + o); o += (size_t)2 * NP;
    int* cur  = (int*)(ws + o); o += (size_t)2 * NP;
    int* incl = (int*)(ws + o); o += (size_t)2 * NP;
    int* tot  = (int*)(ws + o); o += 512;
    int* ttop = (int*)(ws + o); o += 512;
    int* perm = (int*)(ws + o); o += (size_t)2 * NEDGES;
    // overlay group: qn/kn/nWn dead after k_edge_scores, s_n dead after k_gatherA.
    // wsum4 (NP*256 bf16 = NP*128 float-slots) aliases the group (NP*96 + NEDGES*4 slots).
    size_t oG = o;
    u16t* qn   = (u16t*)(ws + o); o += (size_t)NP * 32;
    u16t* kn   = (u16t*)(ws + o); o += (size_t)NP * 32;
    u16t* nWn  = (u16t*)(ws + o); o += (size_t)NP * 32;
    float* s_n = ws + o; o += (size_t)NEDGES * 4;
    u16t* wsum4 = (u16t*)(ws + oG);
    if (ws_size < o * sizeof(float)) return;  // not enough scratch: fail visibly

    // CSR build
    k_zero<<<392, 256, 0, stream>>>(cnt);
    k_hist<<<3125, 256, 0, stream>>>(eidx, cnt);
    k_scan_blk<<<392, 256, 0, stream>>>(cnt, incl, tot);
    k_scan_top<<<1, 512, 0, stream>>>(tot, ttop);
    k_scan_add<<<392, 256, 0, stream>>>(cnt, incl, ttop, ofs, cur);
    k_fill<<<3125, 256, 0, stream>>>(eidx, cur, perm);
    // exact per-head fold matrix
    k_wbig<<<64, 256, 0, stream>>>(Wv_e, Wo_e, Wbig);
    // main pipeline
    k_node_proj<<<196, 256, 0, stream>>>(nodes, Wq_n, Wk_n, Wv_n, Wn_e, qn, kn, vn, nWn);
    k_edge_scores<<<3125, 256, 0, stream>>>(edges, eidx, We_n, Wq_e, Wk_e,
                                            qn, kn, nWn, s_n, s_e);
    k_gatherA<<<12500, 256, 0, stream>>>(eidx, ofs, cnt, perm, s_n, vn, msg);
    k_gatherB<<<12500, 256, 0, stream>>>(edges, ofs, cnt, perm, s_e, wsum4);
    k_node_update<<<196, 256, 0, stream>>>(msg, Wo_n, nodes, newN);
    k_node_update256<<<196, 256, 0, stream>>>(wsum4, Wbig, pWo);
    k_classifier<<<3125, 256, 0, stream>>>(edges, eidx, newN, pWo, W1, b1, W2, b2, out);
}